// Round 1
// baseline (89348.248 us; speedup 1.0000x reference)
//
#include <hip/hip_runtime.h>
#include <math.h>

#define B_ 8
#define N_ 1024
#define D_ 768
#define H_ 12
#define Y_ 64
#define M_ 3072
#define STEPS_ 12
#define ALPHA_ 0.1f
#define EPS_ 1e-5f
#define BETA_ 0.125f          // 1/sqrt(64), exact
#define NTOK (B_*N_)          // 8192 tokens
#define KQK 1536              // q|k concat columns
#define MIDC 4608             // Aq | Ak | relu_h columns

// ---------------- LayerNorm (two-pass, one block per token) ----------------
__global__ __launch_bounds__(256) void ln_kernel(const float* __restrict__ x,
    const float* __restrict__ gamma, const float* __restrict__ beta,
    float* __restrict__ g)
{
    int row = blockIdx.x;
    const float* xr = x + (size_t)row * D_;
    float* gr = g + (size_t)row * D_;
    int t = threadIdx.x;
    float v0 = xr[t], v1 = xr[t + 256], v2 = xr[t + 512];
    float s = v0 + v1 + v2;
    #pragma unroll
    for (int off = 32; off > 0; off >>= 1) s += __shfl_down(s, off);
    __shared__ float red[8];
    int wid = t >> 6, lane = t & 63;
    if (lane == 0) red[wid] = s;
    __syncthreads();
    if (t == 0) red[0] = (red[0] + red[1] + red[2] + red[3]) * (1.0f / D_);
    __syncthreads();
    float mu = red[0];
    float d0 = v0 - mu, d1 = v1 - mu, d2 = v2 - mu;
    float ss = d0*d0 + d1*d1 + d2*d2;
    #pragma unroll
    for (int off = 32; off > 0; off >>= 1) ss += __shfl_down(ss, off);
    if (lane == 0) red[4 + wid] = ss;
    __syncthreads();
    if (t == 0) red[4] = rsqrtf((red[4] + red[5] + red[6] + red[7]) * (1.0f / D_) + EPS_);
    __syncthreads();
    float rs = red[4];
    gr[t]       = gamma[t]       * d0 * rs + beta[t];
    gr[t + 256] = gamma[t + 256] * d1 * rs + beta[t + 256];
    gr[t + 512] = gamma[t + 512] * d2 * rs + beta[t + 512];
}

// ---------------- Generic fp32 tiled GEMM: 64x64 tile, 256 thr, 4x4 micro ----
// BT=true : C[m,n] = sum_k A[m,k]*B[n,k]   (B row-major [N,K])
// BT=false: C[m,n] = sum_k A[m,k]*B[k,n]   (B row-major [K,N])
// EPI: 0 = store, 1 = relu-store, 2 = C += alpha*acc
template<bool BT, int EPI>
__global__ __launch_bounds__(256) void gemm64(
    const float* __restrict__ A, int lda,
    const float* __restrict__ Bm, int ldb,
    float* __restrict__ C, int ldc, int K, float alpha)
{
    __shared__ __align__(16) float As[16][68];
    __shared__ __align__(16) float Bs[16][68];
    int bm = blockIdx.x * 64, bn = blockIdx.y * 64;
    int t = threadIdx.x;
    int tm = t >> 4, tn = t & 15;
    const int kk = t & 15;
    const int rr = t >> 4;
    float acc[4][4] = {};
    for (int k0 = 0; k0 < K; k0 += 16) {
        #pragma unroll
        for (int p = 0; p < 4; ++p)
            As[kk][rr + 16*p] = A[(size_t)(bm + rr + 16*p) * lda + k0 + kk];
        if (BT) {
            #pragma unroll
            for (int p = 0; p < 4; ++p)
                Bs[kk][rr + 16*p] = Bm[(size_t)(bn + rr + 16*p) * ldb + k0 + kk];
        } else {
            int nn = t & 63, kb = t >> 6;
            #pragma unroll
            for (int p = 0; p < 4; ++p)
                Bs[kb + 4*p][nn] = Bm[(size_t)(k0 + kb + 4*p) * ldb + bn + nn];
        }
        __syncthreads();
        #pragma unroll
        for (int k = 0; k < 16; ++k) {
            float4 a4 = *(const float4*)&As[k][tm * 4];
            float4 b4 = *(const float4*)&Bs[k][tn * 4];
            float a[4] = {a4.x, a4.y, a4.z, a4.w};
            float b[4] = {b4.x, b4.y, b4.z, b4.w};
            #pragma unroll
            for (int i = 0; i < 4; ++i)
                #pragma unroll
                for (int j = 0; j < 4; ++j)
                    acc[i][j] = fmaf(a[i], b[j], acc[i][j]);
        }
        __syncthreads();
    }
    #pragma unroll
    for (int i = 0; i < 4; ++i) {
        size_t row = bm + tm * 4 + i;
        #pragma unroll
        for (int j = 0; j < 4; ++j) {
            size_t idx = row * (size_t)ldc + bn + tn * 4 + j;
            if (EPI == 0)      C[idx] = acc[i][j];
            else if (EPI == 1) C[idx] = fmaxf(acc[i][j], 0.0f);
            else               C[idx] += alpha * acc[i][j];
        }
    }
}

// ---------------- LSE over k axis: L[b,h,q] = logsumexp_k(beta*k.q) ---------
__global__ __launch_bounds__(256) void lse_kernel(const float* __restrict__ qk,
                                                  float* __restrict__ L)
{
    int bh = blockIdx.y;              // b*H + h
    int q0 = blockIdx.x << 6;
    int b = bh / H_, h = bh % H_;
    const float* qbase = qk + (size_t)b * N_ * KQK + h * Y_;
    const float* kbase = qbase + 768;
    __shared__ __align__(16) float Ks[64][68];
    __shared__ float Mred[64][4];
    __shared__ float Sred[64][4];
    int t = threadIdx.x, tq = t & 63, tg = t >> 6;
    float qreg[64];
    {
        const float* qr = qbase + (size_t)(q0 + tq) * KQK;
        #pragma unroll
        for (int y4 = 0; y4 < 16; ++y4) {
            float4 v = *(const float4*)(qr + y4 * 4);
            qreg[y4*4+0] = v.x; qreg[y4*4+1] = v.y;
            qreg[y4*4+2] = v.z; qreg[y4*4+3] = v.w;
        }
    }
    float m = -INFINITY, ssum = 0.0f;
    for (int kt = 0; kt < 16; ++kt) {
        __syncthreads();
        #pragma unroll
        for (int jj = 0; jj < 16; ++jj) {
            int idx = t + 256 * jj; int r = idx >> 6, y = idx & 63;
            Ks[r][y] = kbase[(size_t)(kt * 64 + r) * KQK + y];
        }
        __syncthreads();
        #pragma unroll
        for (int j = 0; j < 16; ++j) {
            int kx = tg * 16 + j;
            float s = 0.0f;
            #pragma unroll
            for (int y4 = 0; y4 < 16; ++y4) {
                float4 kv = *(const float4*)&Ks[kx][y4 * 4];
                s = fmaf(qreg[y4*4+0], kv.x, s);
                s = fmaf(qreg[y4*4+1], kv.y, s);
                s = fmaf(qreg[y4*4+2], kv.z, s);
                s = fmaf(qreg[y4*4+3], kv.w, s);
            }
            s *= BETA_;
            if (s > m) { ssum = ssum * __expf(m - s) + 1.0f; m = s; }
            else       { ssum += __expf(s - m); }
        }
    }
    Mred[tq][tg] = m; Sred[tq][tg] = ssum;
    __syncthreads();
    if (tg == 0) {
        float mm = Mred[tq][0], st = Sred[tq][0];
        #pragma unroll
        for (int gi = 1; gi < 4; ++gi) {
            float mo = Mred[tq][gi], so = Sred[tq][gi];
            float mn = fmaxf(mm, mo);
            st = st * __expf(mm - mn) + so * __expf(mo - mn);
            mm = mn;
        }
        L[(size_t)bh * N_ + q0 + tq] = mm + __logf(st);
    }
}

// ---------------- dq: Aq[q,y] = sum_k exp(beta*k.q - L[q]) * k[y] -----------
__global__ __launch_bounds__(256) void dq_kernel(const float* __restrict__ qk,
    const float* __restrict__ L, float* __restrict__ mid)
{
    int bh = blockIdx.y; int q0 = blockIdx.x << 6;
    int b = bh / H_, h = bh % H_;
    const float* qbase = qk + (size_t)b * N_ * KQK + h * Y_;
    const float* kbase = qbase + 768;
    __shared__ __align__(16) float Ks[64][68];
    __shared__ __align__(16) float Racc[64][65];
    int t = threadIdx.x, tq = t & 63, tg = t >> 6;
    float qreg[64];
    {
        const float* qr = qbase + (size_t)(q0 + tq) * KQK;
        #pragma unroll
        for (int y4 = 0; y4 < 16; ++y4) {
            float4 v = *(const float4*)(qr + y4 * 4);
            qreg[y4*4+0] = v.x; qreg[y4*4+1] = v.y;
            qreg[y4*4+2] = v.z; qreg[y4*4+3] = v.w;
        }
    }
    float lval = L[(size_t)bh * N_ + q0 + tq];
    float acc[64] = {};
    for (int kt = 0; kt < 16; ++kt) {
        __syncthreads();
        #pragma unroll
        for (int jj = 0; jj < 16; ++jj) {
            int idx = t + 256 * jj; int r = idx >> 6, y = idx & 63;
            Ks[r][y] = kbase[(size_t)(kt * 64 + r) * KQK + y];
        }
        __syncthreads();
        #pragma unroll
        for (int j = 0; j < 16; ++j) {
            int kx = tg * 16 + j;
            float s = 0.0f;
            #pragma unroll
            for (int y4 = 0; y4 < 16; ++y4) {
                float4 kv = *(const float4*)&Ks[kx][y4 * 4];
                s = fmaf(qreg[y4*4+0], kv.x, s);
                s = fmaf(qreg[y4*4+1], kv.y, s);
                s = fmaf(qreg[y4*4+2], kv.z, s);
                s = fmaf(qreg[y4*4+3], kv.w, s);
            }
            float p = __expf(s * BETA_ - lval);
            #pragma unroll
            for (int y4 = 0; y4 < 16; ++y4) {
                float4 kv = *(const float4*)&Ks[kx][y4 * 4];
                acc[y4*4+0] = fmaf(p, kv.x, acc[y4*4+0]);
                acc[y4*4+1] = fmaf(p, kv.y, acc[y4*4+1]);
                acc[y4*4+2] = fmaf(p, kv.z, acc[y4*4+2]);
                acc[y4*4+3] = fmaf(p, kv.w, acc[y4*4+3]);
            }
        }
    }
    #pragma unroll
    for (int gi = 0; gi < 4; ++gi) {
        if (tg == gi) {
            if (gi == 0) {
                #pragma unroll
                for (int y = 0; y < 64; ++y) Racc[tq][y] = acc[y];
            } else {
                #pragma unroll
                for (int y = 0; y < 64; ++y) Racc[tq][y] += acc[y];
            }
        }
        __syncthreads();
    }
    float* outb = mid + (size_t)(b * N_ + q0) * MIDC + h * Y_;
    #pragma unroll
    for (int jj = 0; jj < 16; ++jj) {
        int idx = t + 256 * jj; int r = idx >> 6, y = idx & 63;
        outb[(size_t)r * MIDC + y] = Racc[r][y];
    }
}

// ---------------- dk: Ak[k,y] = sum_q exp(beta*k.q - L[q]) * q[y] -----------
__global__ __launch_bounds__(256) void dk_kernel(const float* __restrict__ qk,
    const float* __restrict__ L, float* __restrict__ mid)
{
    int bh = blockIdx.y; int k0 = blockIdx.x << 6;
    int b = bh / H_, h = bh % H_;
    const float* qbase = qk + (size_t)b * N_ * KQK + h * Y_;
    const float* kbase = qbase + 768;
    __shared__ __align__(16) float Qs[64][68];
    __shared__ __align__(16) float Racc[64][65];
    __shared__ float Ls[64];
    int t = threadIdx.x, tk = t & 63, tg = t >> 6;
    float kreg[64];
    {
        const float* kr = kbase + (size_t)(k0 + tk) * KQK;
        #pragma unroll
        for (int y4 = 0; y4 < 16; ++y4) {
            float4 v = *(const float4*)(kr + y4 * 4);
            kreg[y4*4+0] = v.x; kreg[y4*4+1] = v.y;
            kreg[y4*4+2] = v.z; kreg[y4*4+3] = v.w;
        }
    }
    float acc[64] = {};
    for (int qt = 0; qt < 16; ++qt) {
        __syncthreads();
        #pragma unroll
        for (int jj = 0; jj < 16; ++jj) {
            int idx = t + 256 * jj; int r = idx >> 6, y = idx & 63;
            Qs[r][y] = qbase[(size_t)(qt * 64 + r) * KQK + y];
        }
        if (t < 64) Ls[t] = L[(size_t)bh * N_ + qt * 64 + t];
        __syncthreads();
        #pragma unroll
        for (int j = 0; j < 16; ++j) {
            int qq = tg * 16 + j;
            float s = 0.0f;
            #pragma unroll
            for (int y4 = 0; y4 < 16; ++y4) {
                float4 qv = *(const float4*)&Qs[qq][y4 * 4];
                s = fmaf(kreg[y4*4+0], qv.x, s);
                s = fmaf(kreg[y4*4+1], qv.y, s);
                s = fmaf(kreg[y4*4+2], qv.z, s);
                s = fmaf(kreg[y4*4+3], qv.w, s);
            }
            float p = __expf(s * BETA_ - Ls[qq]);
            #pragma unroll
            for (int y4 = 0; y4 < 16; ++y4) {
                float4 qv = *(const float4*)&Qs[qq][y4 * 4];
                acc[y4*4+0] = fmaf(p, qv.x, acc[y4*4+0]);
                acc[y4*4+1] = fmaf(p, qv.y, acc[y4*4+1]);
                acc[y4*4+2] = fmaf(p, qv.z, acc[y4*4+2]);
                acc[y4*4+3] = fmaf(p, qv.w, acc[y4*4+3]);
            }
        }
    }
    #pragma unroll
    for (int gi = 0; gi < 4; ++gi) {
        if (tg == gi) {
            if (gi == 0) {
                #pragma unroll
                for (int y = 0; y < 64; ++y) Racc[tk][y] = acc[y];
            } else {
                #pragma unroll
                for (int y = 0; y < 64; ++y) Racc[tk][y] += acc[y];
            }
        }
        __syncthreads();
    }
    float* outb = mid + (size_t)(b * N_ + k0) * MIDC + 768 + h * Y_;
    #pragma unroll
    for (int jj = 0; jj < 16; ++jj) {
        int idx = t + 256 * jj; int r = idx >> 6, y = idx & 63;
        outb[(size_t)r * MIDC + y] = Racc[r][y];
    }
}

// ---------------------------------------------------------------------------
extern "C" void kernel_launch(void* const* d_in, const int* in_sizes, int n_in,
                              void* d_out, int out_size, void* d_ws, size_t ws_size,
                              hipStream_t stream)
{
    const float* x     = (const float*)d_in[0];
    const float* gamma = (const float*)d_in[1];
    const float* betap = (const float*)d_in[2];
    const float* Wq    = (const float*)d_in[3];
    const float* Wk    = (const float*)d_in[4];
    const float* xi    = (const float*)d_in[5];
    float* xc = (float*)d_out;   // xc lives in d_out; final state IS the output

    char* w = (char*)d_ws;
    float* Wcat = (float*)w;  w += (size_t)MIDC * 768 * 4;     // [Wq;Wk;xi] rows
    float* g    = (float*)w;  w += (size_t)NTOK * 768 * 4;
    float* qk   = (float*)w;  w += (size_t)NTOK * KQK * 4;
    float* mid  = (float*)w;  w += (size_t)NTOK * MIDC * 4;    // Aq|Ak|relu_h
    float* L    = (float*)w;  w += (size_t)B_ * H_ * N_ * 4;
    (void)ws_size; (void)in_sizes; (void)n_in; (void)out_size;

    hipMemcpyAsync(xc, x, (size_t)NTOK * 768 * 4, hipMemcpyDeviceToDevice, stream);
    hipMemcpyAsync(Wcat,             Wq, (size_t)768 * 768 * 4, hipMemcpyDeviceToDevice, stream);
    hipMemcpyAsync(Wcat + 768 * 768, Wk, (size_t)768 * 768 * 4, hipMemcpyDeviceToDevice, stream);
    hipMemcpyAsync(Wcat + 2 * 768 * 768, xi, (size_t)M_ * 768 * 4, hipMemcpyDeviceToDevice, stream);

    for (int step = 0; step < STEPS_; ++step) {
        // g = LN(xc)
        ln_kernel<<<NTOK, 256, 0, stream>>>(xc, gamma, betap, g);
        // qk[:,0:768]=g Wq^T, [:,768:1536]=g Wk^T  (B = first 1536 rows of Wcat)
        gemm64<true, 0><<<dim3(128, 24), 256, 0, stream>>>(g, 768, Wcat, 768, qk, KQK, 768, 0.0f);
        // mid[:,1536:4608] = relu(g xi^T)
        gemm64<true, 1><<<dim3(128, 48), 256, 0, stream>>>(g, 768, xi, 768, mid + 1536, MIDC, 768, 0.0f);
        // L[b,h,q] = logsumexp_k beta k.q
        lse_kernel<<<dim3(16, 96), 256, 0, stream>>>(qk, L);
        // mid[:,0:768] = Aq ; mid[:,768:1536] = Ak
        dq_kernel<<<dim3(16, 96), 256, 0, stream>>>(qk, L, mid);
        dk_kernel<<<dim3(16, 96), 256, 0, stream>>>(qk, L, mid);
        // xc += ALPHA * mid @ Wcat   (K=4608 fused update)
        gemm64<false, 2><<<dim3(128, 12), 256, 0, stream>>>(mid, MIDC, Wcat, 768, xc, 768, MIDC, ALPHA_);
    }
}

// Round 2
// 6201.566 us; speedup vs baseline: 14.4074x; 14.4074x over previous
//
#include <hip/hip_runtime.h>
#include <math.h>

#define H_ 12
#define STEPS_ 12
#define ALPHA_ 0.1f
#define EPS_ 1e-5f
#define BETA_ 0.125f          // 1/sqrt(64)
#define NTOK 8192

typedef unsigned short u16;
typedef __attribute__((ext_vector_type(8))) u16 u16x8;
typedef __attribute__((ext_vector_type(4))) u16 u16x4;
typedef __attribute__((ext_vector_type(4))) float f32x4;
typedef __attribute__((ext_vector_type(8))) __bf16 bf16x8;

__device__ inline u16 f2bf(float x) {
    unsigned u = __float_as_uint(x);
    u += 0x7FFFu + ((u >> 16) & 1u);
    return (u16)(u >> 16);
}

// ---------------- LayerNorm -> bf16 g ----------------
__global__ __launch_bounds__(256) void ln_kernel(const float* __restrict__ x,
    const float* __restrict__ gamma, const float* __restrict__ beta,
    u16* __restrict__ g)
{
    int row = blockIdx.x;
    const float* xr = x + (size_t)row * 768;
    u16* gr = g + (size_t)row * 768;
    int t = threadIdx.x;
    float v0 = xr[t], v1 = xr[t + 256], v2 = xr[t + 512];
    float s = v0 + v1 + v2;
    #pragma unroll
    for (int off = 32; off > 0; off >>= 1) s += __shfl_down(s, off);
    __shared__ float red[8];
    int wid = t >> 6, lane = t & 63;
    if (lane == 0) red[wid] = s;
    __syncthreads();
    if (t == 0) red[0] = (red[0] + red[1] + red[2] + red[3]) * (1.0f / 768.0f);
    __syncthreads();
    float mu = red[0];
    float d0 = v0 - mu, d1 = v1 - mu, d2 = v2 - mu;
    float ss = d0*d0 + d1*d1 + d2*d2;
    #pragma unroll
    for (int off = 32; off > 0; off >>= 1) ss += __shfl_down(ss, off);
    if (lane == 0) red[4 + wid] = ss;
    __syncthreads();
    if (t == 0) red[4] = rsqrtf((red[4] + red[5] + red[6] + red[7]) * (1.0f / 768.0f) + EPS_);
    __syncthreads();
    float rs = red[4];
    gr[t]       = f2bf(gamma[t]       * d0 * rs + beta[t]);
    gr[t + 256] = f2bf(gamma[t + 256] * d1 * rs + beta[t + 256]);
    gr[t + 512] = f2bf(gamma[t + 512] * d2 * rs + beta[t + 512]);
}

// ---------------- fp32 -> bf16 convert ----------------
__global__ __launch_bounds__(256) void convert_bf(const float* __restrict__ src,
                                                  u16* __restrict__ dst, int n4)
{
    int i = blockIdx.x * 256 + threadIdx.x;
    if (i < n4) {
        f32x4 v = *(const f32x4*)&src[i * 4];
        u16x4 o;
        #pragma unroll
        for (int e = 0; e < 4; ++e) o[e] = f2bf(v[e]);
        *(u16x4*)&dst[i * 4] = o;
    }
}

// -------- transpose-convert: Wcat [4608x768] f32 -> WcatT [768x4608] bf16 ----
__global__ __launch_bounds__(256) void transpose_bf(const float* __restrict__ Wq,
    const float* __restrict__ Wk, const float* __restrict__ xi, u16* __restrict__ out)
{
    __shared__ float tile[64][65];
    int rb = blockIdx.x * 64, cb = blockIdx.y * 64;
    const float* src;
    if (rb < 768) src = Wq + (size_t)rb * 768;
    else if (rb < 1536) src = Wk + (size_t)(rb - 768) * 768;
    else src = xi + (size_t)(rb - 1536) * 768;
    int t = threadIdx.x;
    #pragma unroll
    for (int it = 0; it < 4; ++it) {
        int r = (t >> 4) + 16 * it;
        f32x4 v = *(const f32x4*)&src[(size_t)r * 768 + cb + (t & 15) * 4];
        #pragma unroll
        for (int e = 0; e < 4; ++e) tile[r][(t & 15) * 4 + e] = v[e];
    }
    __syncthreads();
    #pragma unroll
    for (int it = 0; it < 4; ++it) {
        int cl = (t >> 4) + 16 * it;
        u16x4 o;
        #pragma unroll
        for (int e = 0; e < 4; ++e) o[e] = f2bf(tile[(t & 15) * 4 + e][cl]);
        *(u16x4*)&out[(size_t)(cb + cl) * 4608 + rb + (t & 15) * 4] = o;
    }
}

// ---------------- MFMA GEMM: C = A * Bt^T (both [rows, K] bf16) -------------
// block 256 = 4 waves in 2x2; wave tile WM x WN; BM=2*WM, BN=2*WN; BK=32.
// LDS fragment-order layout: 16B chunk (row, c) at addr16 = 64*(row>>4)+16*c+(row&15)
// EPI: 0 = bf16 store, 1 = bf16 relu store, 2 = fp32 C += alpha*acc
template<int WM, int WN, int EPI>
__global__ __launch_bounds__(256) void mfma_gemm_bt(
    const u16* __restrict__ A, int lda,
    const u16* __restrict__ Bt, int ldb,
    void* __restrict__ Cv, int ldc, int K, float alpha)
{
    constexpr int BM = 2 * WM, BN = 2 * WN, NI = WM / 16, NJ = WN / 16;
    __shared__ __align__(16) u16 As[BM * 32];
    __shared__ __align__(16) u16 Bs[BN * 32];
    const int t = threadIdx.x, w = t >> 6, l = t & 63, g = l >> 4, cid = l & 15;
    const int bm = blockIdx.x * BM, bn = blockIdx.y * BN;
    const int RO = (w >> 1) * WM, CO = (w & 1) * WN;
    f32x4 acc[NI][NJ] = {};
    for (int k0 = 0; k0 < K; k0 += 32) {
        for (int ch = t; ch < (BM + BN) * 4; ch += 256) {
            int cc = ch, row; const u16* src; u16* dst;
            if (cc < BM * 4) { row = cc >> 2; src = &A[(size_t)(bm + row) * lda + k0 + 8 * (cc & 3)]; dst = As; }
            else { cc -= BM * 4; row = cc >> 2; src = &Bt[(size_t)(bn + row) * ldb + k0 + 8 * (cc & 3)]; dst = Bs; }
            int a16 = 64 * (row >> 4) + 16 * (cc & 3) + (row & 15);
            *(u16x8*)&dst[a16 * 8] = *(const u16x8*)src;
        }
        __syncthreads();
        bf16x8 af[NI], bfr[NJ];
        #pragma unroll
        for (int i = 0; i < NI; ++i) af[i] = *(const bf16x8*)&As[((RO >> 4) + i) * 512 + 8 * l];
        #pragma unroll
        for (int j = 0; j < NJ; ++j) bfr[j] = *(const bf16x8*)&Bs[((CO >> 4) + j) * 512 + 8 * l];
        #pragma unroll
        for (int i = 0; i < NI; ++i)
            #pragma unroll
            for (int j = 0; j < NJ; ++j)
                acc[i][j] = __builtin_amdgcn_mfma_f32_16x16x32_bf16(af[i], bfr[j], acc[i][j], 0, 0, 0);
        __syncthreads();
    }
    #pragma unroll
    for (int i = 0; i < NI; ++i) {
        #pragma unroll
        for (int r = 0; r < 4; ++r) {
            size_t row = bm + RO + 16 * i + 4 * g + r;
            #pragma unroll
            for (int j = 0; j < NJ; ++j) {
                size_t col = bn + CO + 16 * j + cid;
                float v = acc[i][j][r];
                if (EPI == 0)      ((u16*)Cv)[row * ldc + col] = f2bf(v);
                else if (EPI == 1) ((u16*)Cv)[row * ldc + col] = f2bf(fmaxf(v, 0.0f));
                else               ((float*)Cv)[row * ldc + col] += alpha * v;
            }
        }
    }
}

// ---------------- dq: flash pass, computes L and Aq ----------------
// grid (16 q-tiles, 96 bh), block 256. Wave w owns q columns [16w,16w+16).
__global__ __launch_bounds__(256) void dq_kernel(const u16* __restrict__ qk,
    float* __restrict__ L, u16* __restrict__ mid)
{
    const int bh = blockIdx.y, b = bh / H_, h = bh % H_;
    const int q0 = blockIdx.x << 6;
    const u16* qbase = qk + (size_t)b * 1024 * 1536 + h * 64;
    const u16* kbase = qbase + 768;
    __shared__ __align__(16) u16 Qs[4096], Kn[4096], Kt[4096], Ps[4096];
    const int t = threadIdx.x, w = t >> 6, l = t & 63, g = l >> 4, cid = l & 15;

    #pragma unroll
    for (int hh = 0; hh < 2; ++hh) {
        int ch = t + 256 * hh, row = ch >> 3, c = ch & 7;
        int a16 = 128 * (row >> 4) + 16 * c + (row & 15);
        *(u16x8*)&Qs[a16 * 8] = *(const u16x8*)&qbase[(size_t)(q0 + row) * 1536 + 8 * c];
    }
    __syncthreads();

    f32x4 aq[4] = {};
    float mrun = -__builtin_inff(), lrun = 0.0f;

    for (int kt = 0; kt < 16; ++kt) {
        #pragma unroll
        for (int hh = 0; hh < 2; ++hh) {
            int ch = t + 256 * hh, row = ch >> 3, c = ch & 7;
            int a16 = 128 * (row >> 4) + 16 * c + (row & 15);
            u16x8 v = *(const u16x8*)&kbase[(size_t)(kt * 64 + row) * 1536 + 8 * c];
            *(u16x8*)&Kn[a16 * 8] = v;
            #pragma unroll
            for (int e = 0; e < 8; ++e) {
                int y = 8 * c + e;
                Kt[(128 * (y >> 4) + 16 * (row >> 3) + (y & 15)) * 8 + (row & 7)] = v[e];
            }
        }
        __syncthreads();

        // S'[k,q] = K·Q^T : tiles [i][col-block w]
        bf16x8 bq0 = *(const bf16x8*)&Qs[(128 * w + l) * 8];
        bf16x8 bq1 = *(const bf16x8*)&Qs[(128 * w + 64 + l) * 8];
        f32x4 s[4];
        #pragma unroll
        for (int i = 0; i < 4; ++i) {
            f32x4 z = {0.f, 0.f, 0.f, 0.f};
            z = __builtin_amdgcn_mfma_f32_16x16x32_bf16(*(const bf16x8*)&Kn[(128 * i + l) * 8], bq0, z, 0, 0, 0);
            z = __builtin_amdgcn_mfma_f32_16x16x32_bf16(*(const bf16x8*)&Kn[(128 * i + 64 + l) * 8], bq1, z, 0, 0, 0);
            s[i] = z;
        }
        // online softmax per column q = q0 + 16w + cid
        float mloc = -__builtin_inff();
        #pragma unroll
        for (int i = 0; i < 4; ++i)
            #pragma unroll
            for (int r = 0; r < 4; ++r) mloc = fmaxf(mloc, s[i][r]);
        mloc = fmaxf(mloc, __shfl_xor(mloc, 16));
        mloc = fmaxf(mloc, __shfl_xor(mloc, 32));
        float mnew = fmaxf(mrun, BETA_ * mloc);
        float fs = __expf(mrun - mnew);
        float psum = 0.0f;
        #pragma unroll
        for (int i = 0; i < 4; ++i) {
            u16x4 pv;
            #pragma unroll
            for (int r = 0; r < 4; ++r) {
                float p = __expf(fmaf(s[i][r], BETA_, -mnew));
                psum += p;
                pv[r] = f2bf(p);
            }
            // P'^T[q, k]: row q=16w+cid, k = 16i+4g+r (4 contiguous) -> b64 write
            *(u16x4*)&Ps[1024 * w + 256 * i + 128 * (g >> 1) + 8 * cid + 4 * (g & 1)] = pv;
        }
        psum += __shfl_xor(psum, 16);
        psum += __shfl_xor(psum, 32);
        lrun = lrun * fs + psum;
        mrun = mnew;
        // rescale Aq rows (row q = 16w+4g+r gets factor from lane cid==4g+r)
        #pragma unroll
        for (int r = 0; r < 4; ++r) {
            float fr = __shfl(fs, 4 * g + r);
            #pragma unroll
            for (int j = 0; j < 4; ++j) aq[j][r] *= fr;
        }
        // Aq[q,y] += P'^T · Kt^T
        bf16x8 ap0 = *(const bf16x8*)&Ps[(128 * w + l) * 8];
        bf16x8 ap1 = *(const bf16x8*)&Ps[(128 * w + 64 + l) * 8];
        #pragma unroll
        for (int j = 0; j < 4; ++j) {
            aq[j] = __builtin_amdgcn_mfma_f32_16x16x32_bf16(ap0, *(const bf16x8*)&Kt[(128 * j + l) * 8], aq[j], 0, 0, 0);
            aq[j] = __builtin_amdgcn_mfma_f32_16x16x32_bf16(ap1, *(const bf16x8*)&Kt[(128 * j + 64 + l) * 8], aq[j], 0, 0, 0);
        }
        __syncthreads();
    }
    if (g == 0) L[(size_t)bh * 1024 + q0 + 16 * w + cid] = mrun + __logf(lrun);
    float linv = 1.0f / lrun;
    u16* outb = mid + (size_t)(b * 1024 + q0) * 4608 + h * 64;
    #pragma unroll
    for (int r = 0; r < 4; ++r) {
        float lr = __shfl(linv, 4 * g + r);
        int row = 16 * w + 4 * g + r;
        #pragma unroll
        for (int j = 0; j < 4; ++j)
            outb[(size_t)row * 4608 + 16 * j + cid] = f2bf(aq[j][r] * lr);
    }
}

// ---------------- dk: Ak[k,y] = sum_q exp(beta*S - L[q]) q[y] ----------------
// grid (16 k-tiles, 96 bh). Wave w owns k columns [16w,16w+16).
__global__ __launch_bounds__(256) void dk_kernel(const u16* __restrict__ qk,
    const float* __restrict__ L, u16* __restrict__ mid)
{
    const int bh = blockIdx.y, b = bh / H_, h = bh % H_;
    const int k0 = blockIdx.x << 6;
    const u16* qbase = qk + (size_t)b * 1024 * 1536 + h * 64;
    const u16* kbase = qbase + 768;
    __shared__ __align__(16) u16 Kr[4096], Qn[4096], Qt[4096], Ps[4096];
    __shared__ float Ls[64];
    const int t = threadIdx.x, w = t >> 6, l = t & 63, g = l >> 4, cid = l & 15;

    #pragma unroll
    for (int hh = 0; hh < 2; ++hh) {
        int ch = t + 256 * hh, row = ch >> 3, c = ch & 7;
        int a16 = 128 * (row >> 4) + 16 * c + (row & 15);
        *(u16x8*)&Kr[a16 * 8] = *(const u16x8*)&kbase[(size_t)(k0 + row) * 1536 + 8 * c];
    }
    __syncthreads();

    f32x4 ak[4] = {};
    for (int qt = 0; qt < 16; ++qt) {
        #pragma unroll
        for (int hh = 0; hh < 2; ++hh) {
            int ch = t + 256 * hh, row = ch >> 3, c = ch & 7;
            int a16 = 128 * (row >> 4) + 16 * c + (row & 15);
            u16x8 v = *(const u16x8*)&qbase[(size_t)(qt * 64 + row) * 1536 + 8 * c];
            *(u16x8*)&Qn[a16 * 8] = v;
            #pragma unroll
            for (int e = 0; e < 8; ++e) {
                int y = 8 * c + e;
                Qt[(128 * (y >> 4) + 16 * (row >> 3) + (y & 15)) * 8 + (row & 7)] = v[e];
            }
        }
        if (t < 64) Ls[t] = L[(size_t)bh * 1024 + qt * 64 + t];
        __syncthreads();

        // S''[q,k] = Q·K^T : tiles [i][col-block w]; P'' = exp(beta*S - L[q])
        bf16x8 bk0 = *(const bf16x8*)&Kr[(128 * w + l) * 8];
        bf16x8 bk1 = *(const bf16x8*)&Kr[(128 * w + 64 + l) * 8];
        #pragma unroll
        for (int i = 0; i < 4; ++i) {
            f32x4 z = {0.f, 0.f, 0.f, 0.f};
            z = __builtin_amdgcn_mfma_f32_16x16x32_bf16(*(const bf16x8*)&Qn[(128 * i + l) * 8], bk0, z, 0, 0, 0);
            z = __builtin_amdgcn_mfma_f32_16x16x32_bf16(*(const bf16x8*)&Qn[(128 * i + 64 + l) * 8], bk1, z, 0, 0, 0);
            f32x4 lv = *(const f32x4*)&Ls[16 * i + 4 * g];
            u16x4 pv;
            #pragma unroll
            for (int r = 0; r < 4; ++r)
                pv[r] = f2bf(__expf(fmaf(z[r], BETA_, -lv[r])));
            // P''^T[k, q]: row k=16w+cid, q = 16i+4g+r -> b64 write
            *(u16x4*)&Ps[1024 * w + 256 * i + 128 * (g >> 1) + 8 * cid + 4 * (g & 1)] = pv;
        }
        // Ak[k,y] += P''^T · Qt^T
        bf16x8 ap0 = *(const bf16x8*)&Ps[(128 * w + l) * 8];
        bf16x8 ap1 = *(const bf16x8*)&Ps[(128 * w + 64 + l) * 8];
        #pragma unroll
        for (int j = 0; j < 4; ++j) {
            ak[j] = __builtin_amdgcn_mfma_f32_16x16x32_bf16(ap0, *(const bf16x8*)&Qt[(128 * j + l) * 8], ak[j], 0, 0, 0);
            ak[j] = __builtin_amdgcn_mfma_f32_16x16x32_bf16(ap1, *(const bf16x8*)&Qt[(128 * j + 64 + l) * 8], ak[j], 0, 0, 0);
        }
        __syncthreads();
    }
    u16* outb = mid + (size_t)(b * 1024 + k0) * 4608 + 768 + h * 64;
    #pragma unroll
    for (int r = 0; r < 4; ++r) {
        int row = 16 * w + 4 * g + r;
        #pragma unroll
        for (int j = 0; j < 4; ++j)
            outb[(size_t)row * 4608 + 16 * j + cid] = f2bf(ak[j][r]);
    }
}

// ---------------------------------------------------------------------------
extern "C" void kernel_launch(void* const* d_in, const int* in_sizes, int n_in,
                              void* d_out, int out_size, void* d_ws, size_t ws_size,
                              hipStream_t stream)
{
    const float* x     = (const float*)d_in[0];
    const float* gamma = (const float*)d_in[1];
    const float* betap = (const float*)d_in[2];
    const float* Wq    = (const float*)d_in[3];
    const float* Wk    = (const float*)d_in[4];
    const float* xi    = (const float*)d_in[5];
    float* xc = (float*)d_out;

    char* p = (char*)d_ws;
    u16* wqk_bf   = (u16*)p; p += (size_t)1536 * 768 * 2;
    u16* xi_bf    = (u16*)p; p += (size_t)3072 * 768 * 2;
    u16* wcatT_bf = (u16*)p; p += (size_t)768 * 4608 * 2;
    u16* g_bf     = (u16*)p; p += (size_t)NTOK * 768 * 2;
    u16* qk_bf    = (u16*)p; p += (size_t)NTOK * 1536 * 2;
    u16* mid_bf   = (u16*)p; p += (size_t)NTOK * 4608 * 2;
    float* L      = (float*)p; p += (size_t)96 * 1024 * 4;
    (void)ws_size; (void)in_sizes; (void)n_in; (void)out_size;

    hipMemcpyAsync(xc, x, (size_t)NTOK * 768 * 4, hipMemcpyDeviceToDevice, stream);

    // weight conversion (idempotent per launch)
    convert_bf<<<576, 256, 0, stream>>>(Wq, wqk_bf, 147456);
    convert_bf<<<576, 256, 0, stream>>>(Wk, wqk_bf + 768 * 768, 147456);
    convert_bf<<<2304, 256, 0, stream>>>(xi, xi_bf, 589824);
    transpose_bf<<<dim3(72, 12), 256, 0, stream>>>(Wq, Wk, xi, wcatT_bf);

    for (int step = 0; step < STEPS_; ++step) {
        ln_kernel<<<NTOK, 256, 0, stream>>>(xc, gamma, betap, g_bf);
        // qk = g·[Wq;Wk]^T  (bf16 out)
        mfma_gemm_bt<32, 64, 0><<<dim3(128, 12), 256, 0, stream>>>(
            g_bf, 768, wqk_bf, 768, qk_bf, 1536, 768, 0.0f);
        // mid[:,1536:] = relu(g·xi^T)
        mfma_gemm_bt<32, 64, 1><<<dim3(128, 24), 256, 0, stream>>>(
            g_bf, 768, xi_bf, 768, mid_bf + 1536, 4608, 768, 0.0f);
        // Aq (+L), Ak
        dq_kernel<<<dim3(16, 96), 256, 0, stream>>>(qk_bf, L, mid_bf);
        dk_kernel<<<dim3(16, 96), 256, 0, stream>>>(qk_bf, L, mid_bf);
        // xc += alpha * mid · Wcat  (K=4608 fused)
        mfma_gemm_bt<32, 32, 2><<<dim3(128, 12), 256, 0, stream>>>(
            mid_bf, 4608, wcatT_bf, 4608, xc, 768, 4608, ALPHA_);
    }
}

// Round 3
// 4598.829 us; speedup vs baseline: 19.4285x; 1.3485x over previous
//
#include <hip/hip_runtime.h>
#include <math.h>

#define H_ 12
#define STEPS_ 12
#define ALPHA_ 0.1f
#define EPS_ 1e-5f
#define BETA_ 0.125f          // 1/sqrt(64)
#define NTOK 8192

typedef unsigned short u16;
typedef __attribute__((ext_vector_type(8))) u16 u16x8;
typedef __attribute__((ext_vector_type(4))) u16 u16x4;
typedef __attribute__((ext_vector_type(4))) float f32x4;
typedef __attribute__((ext_vector_type(8))) __bf16 bf16x8;

#define MFMA __builtin_amdgcn_mfma_f32_16x16x32_bf16

__device__ __forceinline__ u16 f2bf(float x) {
    unsigned u = __float_as_uint(x);
    u += 0x7FFFu + ((u >> 16) & 1u);
    return (u16)(u >> 16);
}

// async global->LDS, 16B per lane; LDS dst must be lane-linear (base + 16*lane)
__device__ __forceinline__ void gl2lds16(const u16* gsrc, u16* ldst) {
    __builtin_amdgcn_global_load_lds(
        (const __attribute__((address_space(1))) void*)gsrc,
        (__attribute__((address_space(3))) void*)ldst, 16, 0, 0);
}

// ---------------- LayerNorm -> bf16 g ----------------
__global__ __launch_bounds__(256) void ln_kernel(const float* __restrict__ x,
    const float* __restrict__ gamma, const float* __restrict__ beta,
    u16* __restrict__ g)
{
    int row = blockIdx.x;
    const float* xr = x + (size_t)row * 768;
    u16* gr = g + (size_t)row * 768;
    int t = threadIdx.x;
    float v0 = xr[t], v1 = xr[t + 256], v2 = xr[t + 512];
    float s = v0 + v1 + v2;
    #pragma unroll
    for (int off = 32; off > 0; off >>= 1) s += __shfl_down(s, off);
    __shared__ float red[8];
    int wid = t >> 6, lane = t & 63;
    if (lane == 0) red[wid] = s;
    __syncthreads();
    if (t == 0) red[0] = (red[0] + red[1] + red[2] + red[3]) * (1.0f / 768.0f);
    __syncthreads();
    float mu = red[0];
    float d0 = v0 - mu, d1 = v1 - mu, d2 = v2 - mu;
    float ss = d0*d0 + d1*d1 + d2*d2;
    #pragma unroll
    for (int off = 32; off > 0; off >>= 1) ss += __shfl_down(ss, off);
    if (lane == 0) red[4 + wid] = ss;
    __syncthreads();
    if (t == 0) red[4] = rsqrtf((red[4] + red[5] + red[6] + red[7]) * (1.0f / 768.0f) + EPS_);
    __syncthreads();
    float rs = red[4];
    gr[t]       = f2bf(gamma[t]       * d0 * rs + beta[t]);
    gr[t + 256] = f2bf(gamma[t + 256] * d1 * rs + beta[t + 256]);
    gr[t + 512] = f2bf(gamma[t + 512] * d2 * rs + beta[t + 512]);
}

// ---------------- fp32 -> bf16 convert ----------------
__global__ __launch_bounds__(256) void convert_bf(const float* __restrict__ src,
                                                  u16* __restrict__ dst, int n4)
{
    int i = blockIdx.x * 256 + threadIdx.x;
    if (i < n4) {
        f32x4 v = *(const f32x4*)&src[i * 4];
        u16x4 o;
        #pragma unroll
        for (int e = 0; e < 4; ++e) o[e] = f2bf(v[e]);
        *(u16x4*)&dst[i * 4] = o;
    }
}

// -------- transpose-convert: Wcat [4608x768] f32 -> WcatT [768x4608] bf16 ----
__global__ __launch_bounds__(256) void transpose_bf(const float* __restrict__ Wq,
    const float* __restrict__ Wk, const float* __restrict__ xi, u16* __restrict__ out)
{
    __shared__ float tile[64][65];
    int rb = blockIdx.x * 64, cb = blockIdx.y * 64;
    const float* src;
    if (rb < 768) src = Wq + (size_t)rb * 768;
    else if (rb < 1536) src = Wk + (size_t)(rb - 768) * 768;
    else src = xi + (size_t)(rb - 1536) * 768;
    int t = threadIdx.x;
    #pragma unroll
    for (int it = 0; it < 4; ++it) {
        int r = (t >> 4) + 16 * it;
        f32x4 v = *(const f32x4*)&src[(size_t)r * 768 + cb + (t & 15) * 4];
        #pragma unroll
        for (int e = 0; e < 4; ++e) tile[r][(t & 15) * 4 + e] = v[e];
    }
    __syncthreads();
    #pragma unroll
    for (int it = 0; it < 4; ++it) {
        int cl = (t >> 4) + 16 * it;
        u16x4 o;
        #pragma unroll
        for (int e = 0; e < 4; ++e) o[e] = f2bf(tile[(t & 15) * 4 + e][cl]);
        *(u16x4*)&out[(size_t)(cb + cl) * 4608 + rb + (t & 15) * 4] = o;
    }
}

// ---------------- m97-style MFMA GEMM: C = A * Bt^T, 128x128 tile, BK=32 ----
// 4 waves 2x2, wave tile 64x64 (4x4 of 16x16x32), global_load_lds staging.
// LDS frag layout: 16B chunk (row, c) at idx16 = 64*(row>>4) + 16*c + (row&15)
// EPI: 0 = bf16 store, 1 = bf16 relu store, 2 = fp32 C += alpha*acc,
//      3 = bf16 store + transposed qkT[b,h,sel,y,token] dual write
template<int EPI>
__global__ __launch_bounds__(256) void gemm128(
    const u16* __restrict__ A, int lda,
    const u16* __restrict__ Bt, int ldb,
    void* __restrict__ Cv, int ldc, int K, float alpha, u16* __restrict__ qkT)
{
    __shared__ __align__(16) u16 As[128 * 32];
    __shared__ __align__(16) u16 Bs[128 * 32];
    const int t = threadIdx.x, w = t >> 6, l = t & 63, g = l >> 4, cid = l & 15;
    const int lr = l & 15, lc = l >> 4;
    const int bm = blockIdx.x * 128, bn = blockIdx.y * 128;
    const int RO = (w >> 1) * 64, CO = (w & 1) * 64;
    f32x4 acc[4][4] = {};
    for (int k0 = 0; k0 < K; k0 += 32) {
        __syncthreads();
        #pragma unroll
        for (int half = 0; half < 2; ++half) {
            int R0 = 32 * w + 16 * half;
            gl2lds16(&A [(size_t)(bm + R0 + lr) * lda + k0 + 8 * lc], &As[(64 * (2*w + half) + l) * 8]);
            gl2lds16(&Bt[(size_t)(bn + R0 + lr) * ldb + k0 + 8 * lc], &Bs[(64 * (2*w + half) + l) * 8]);
        }
        __syncthreads();
        bf16x8 af[4], bfr[4];
        #pragma unroll
        for (int i = 0; i < 4; ++i) af[i]  = *(const bf16x8*)&As[(64 * ((RO >> 4) + i) + l) * 8];
        #pragma unroll
        for (int j = 0; j < 4; ++j) bfr[j] = *(const bf16x8*)&Bs[(64 * ((CO >> 4) + j) + l) * 8];
        #pragma unroll
        for (int i = 0; i < 4; ++i)
            #pragma unroll
            for (int j = 0; j < 4; ++j)
                acc[i][j] = MFMA(af[i], bfr[j], acc[i][j], 0, 0, 0);
    }
    // epilogue
    if (EPI == 3) {
        int bidx = bm >> 10;
        #pragma unroll
        for (int i = 0; i < 4; ++i) {
            int tok = bm + RO + 16 * i + 4 * g;      // 4 consecutive tokens (r)
            #pragma unroll
            for (int j = 0; j < 4; ++j) {
                int col = bn + CO + 16 * j + cid;
                int sel = col >= 768 ? 1 : 0;
                int cc = col - 768 * sel;
                int hh = cc >> 6, yy = cc & 63;
                u16x4 tv;
                #pragma unroll
                for (int r = 0; r < 4; ++r) {
                    u16 bv = f2bf(acc[i][j][r]);
                    tv[r] = bv;
                    ((u16*)Cv)[(size_t)(tok + r) * ldc + col] = bv;
                }
                *(u16x4*)&qkT[((((size_t)bidx * 12 + hh) * 2 + sel) * 64 + yy) * 1024 + (tok & 1023)] = tv;
            }
        }
    } else {
        #pragma unroll
        for (int i = 0; i < 4; ++i)
            #pragma unroll
            for (int r = 0; r < 4; ++r) {
                size_t row = bm + RO + 16 * i + 4 * g + r;
                #pragma unroll
                for (int j = 0; j < 4; ++j) {
                    size_t idx = row * (size_t)ldc + bn + CO + 16 * j + cid;
                    float v = acc[i][j][r];
                    if (EPI == 0)      ((u16*)Cv)[idx] = f2bf(v);
                    else if (EPI == 1) ((u16*)Cv)[idx] = f2bf(fmaxf(v, 0.0f));
                    else               ((float*)Cv)[idx] += alpha * v;
                }
            }
    }
}

// ---------------- dq: flash pass over k, 128-q tile, computes L and Aq -------
// grid (8, 96). Wave w owns q columns [32w, 32w+32) as 2 jj-halves of 16.
__global__ __launch_bounds__(256) void dq_kernel(const u16* __restrict__ qk,
    const u16* __restrict__ qkT, float* __restrict__ L, u16* __restrict__ mid)
{
    const int bh = blockIdx.y, b = bh / H_, h = bh % H_;
    const int q0 = blockIdx.x << 7;
    const u16* qbase = qk + (size_t)b * 1024 * 1536 + h * 64;
    const u16* kbase = qbase + 768;
    const u16* ktg = qkT + ((size_t)bh * 2 + 1) * 64 * 1024;   // K^T [y][1024]
    __shared__ __align__(16) u16 Qs[128 * 64], Kn[64 * 64], Kt[64 * 64], Ps[128 * 64];
    const int t = threadIdx.x, w = t >> 6, l = t & 63, g = l >> 4, cid = l & 15;
    const int lr = l & 15, lc = l >> 4;

    // stage Q tile once (128 q rows x 64 y)
    #pragma unroll
    for (int h2 = 0; h2 < 2; ++h2)
        #pragma unroll
        for (int ch = 0; ch < 2; ++ch)
            gl2lds16(&qbase[(size_t)(q0 + 32 * w + 16 * h2 + lr) * 1536 + 32 * ch + 8 * lc],
                     &Qs[(128 * (2 * w + h2) + 64 * ch + l) * 8]);
    __syncthreads();
    bf16x8 QF[2][2];
    #pragma unroll
    for (int jj = 0; jj < 2; ++jj)
        #pragma unroll
        for (int hh = 0; hh < 2; ++hh)
            QF[jj][hh] = *(const bf16x8*)&Qs[(128 * (2 * w + jj) + 64 * hh + l) * 8];

    f32x4 acc[2][4] = {};
    float mrun[2] = {-__builtin_inff(), -__builtin_inff()};
    float lrun[2] = {0.0f, 0.0f};

    for (int kt = 0; kt < 16; ++kt) {
        __syncthreads();
        #pragma unroll
        for (int ch = 0; ch < 2; ++ch) {
            gl2lds16(&kbase[(size_t)(kt * 64 + 16 * w + lr) * 1536 + 32 * ch + 8 * lc],
                     &Kn[(128 * w + 64 * ch + l) * 8]);
            gl2lds16(&ktg[(size_t)(16 * w + lr) * 1024 + kt * 64 + 32 * ch + 8 * lc],
                     &Kt[(128 * w + 64 * ch + l) * 8]);
        }
        __syncthreads();
        // S'[k][q] tiles: rows k (4 i-tiles), cols q (2 jj per wave)
        f32x4 s[4][2];
        #pragma unroll
        for (int i = 0; i < 4; ++i) {
            bf16x8 a0 = *(const bf16x8*)&Kn[(128 * i + l) * 8];
            bf16x8 a1 = *(const bf16x8*)&Kn[(128 * i + 64 + l) * 8];
            #pragma unroll
            for (int jj = 0; jj < 2; ++jj) {
                f32x4 z = {0.f, 0.f, 0.f, 0.f};
                z = MFMA(a0, QF[jj][0], z, 0, 0, 0);
                z = MFMA(a1, QF[jj][1], z, 0, 0, 0);
                s[i][jj] = z;
            }
        }
        // online softmax per jj (col q = 32w + 16jj + cid)
        #pragma unroll
        for (int jj = 0; jj < 2; ++jj) {
            float mloc = -__builtin_inff();
            #pragma unroll
            for (int i = 0; i < 4; ++i)
                #pragma unroll
                for (int r = 0; r < 4; ++r) mloc = fmaxf(mloc, s[i][jj][r]);
            mloc = fmaxf(mloc, __shfl_xor(mloc, 16));
            mloc = fmaxf(mloc, __shfl_xor(mloc, 32));
            float mnew = fmaxf(mrun[jj], BETA_ * mloc);
            float fs = __expf(mrun[jj] - mnew);
            float psum = 0.0f;
            #pragma unroll
            for (int i = 0; i < 4; ++i) {
                u16x4 pv;
                #pragma unroll
                for (int r = 0; r < 4; ++r) {
                    float p = __expf(fmaf(s[i][jj][r], BETA_, -mnew));
                    psum += p;
                    pv[r] = f2bf(p);
                }
                *(u16x4*)&Ps[(128 * (2 * w + jj) + 32 * i + 16 * (g >> 1) + cid) * 8 + 4 * (g & 1)] = pv;
            }
            psum += __shfl_xor(psum, 16);
            psum += __shfl_xor(psum, 32);
            lrun[jj] = lrun[jj] * fs + psum;
            mrun[jj] = mnew;
            #pragma unroll
            for (int r = 0; r < 4; ++r) {
                float fr = __shfl(fs, 4 * g + r);
                #pragma unroll
                for (int j = 0; j < 4; ++j) acc[jj][j][r] *= fr;
            }
        }
        // Aq += P'^T . K  (A = Ps rows q, B = Kt rows y)
        #pragma unroll
        for (int jj = 0; jj < 2; ++jj) {
            bf16x8 p0 = *(const bf16x8*)&Ps[(128 * (2 * w + jj) + l) * 8];
            bf16x8 p1 = *(const bf16x8*)&Ps[(128 * (2 * w + jj) + 64 + l) * 8];
            #pragma unroll
            for (int j = 0; j < 4; ++j) {
                acc[jj][j] = MFMA(p0, *(const bf16x8*)&Kt[(128 * j + l) * 8], acc[jj][j], 0, 0, 0);
                acc[jj][j] = MFMA(p1, *(const bf16x8*)&Kt[(128 * j + 64 + l) * 8], acc[jj][j], 0, 0, 0);
            }
        }
    }
    #pragma unroll
    for (int jj = 0; jj < 2; ++jj) {
        if (g == 0)
            L[(size_t)bh * 1024 + q0 + 32 * w + 16 * jj + cid] = mrun[jj] + __logf(lrun[jj]);
        float linv = 1.0f / lrun[jj];
        #pragma unroll
        for (int r = 0; r < 4; ++r) {
            float fr = __shfl(linv, 4 * g + r);
            int row = q0 + 32 * w + 16 * jj + 4 * g + r;
            #pragma unroll
            for (int j = 0; j < 4; ++j)
                mid[(size_t)(b * 1024 + row) * 4608 + h * 64 + 16 * j + cid] = f2bf(acc[jj][j][r] * fr);
        }
    }
}

// ---------------- dk: Ak[k] = sum_q exp(beta*S - L[q]) q, 128-k tile --------
__global__ __launch_bounds__(256) void dk_kernel(const u16* __restrict__ qk,
    const u16* __restrict__ qkT, const float* __restrict__ L, u16* __restrict__ mid)
{
    const int bh = blockIdx.y, b = bh / H_, h = bh % H_;
    const int k0 = blockIdx.x << 7;
    const u16* qbase = qk + (size_t)b * 1024 * 1536 + h * 64;
    const u16* kbase = qbase + 768;
    const u16* qtg = qkT + ((size_t)bh * 2 + 0) * 64 * 1024;   // Q^T [y][1024]
    __shared__ __align__(16) u16 Kr[128 * 64], Qn[64 * 64], Qt[64 * 64], Ps[128 * 64];
    __shared__ __align__(16) float Ls[64];
    const int t = threadIdx.x, w = t >> 6, l = t & 63, g = l >> 4, cid = l & 15;
    const int lr = l & 15, lc = l >> 4;

    // stage K tile once (128 k rows x 64 y)
    #pragma unroll
    for (int h2 = 0; h2 < 2; ++h2)
        #pragma unroll
        for (int ch = 0; ch < 2; ++ch)
            gl2lds16(&kbase[(size_t)(k0 + 32 * w + 16 * h2 + lr) * 1536 + 32 * ch + 8 * lc],
                     &Kr[(128 * (2 * w + h2) + 64 * ch + l) * 8]);
    __syncthreads();
    bf16x8 KF[2][2];
    #pragma unroll
    for (int jj = 0; jj < 2; ++jj)
        #pragma unroll
        for (int hh = 0; hh < 2; ++hh)
            KF[jj][hh] = *(const bf16x8*)&Kr[(128 * (2 * w + jj) + 64 * hh + l) * 8];

    f32x4 acc[2][4] = {};
    for (int qt = 0; qt < 16; ++qt) {
        __syncthreads();
        #pragma unroll
        for (int ch = 0; ch < 2; ++ch) {
            gl2lds16(&qbase[(size_t)(qt * 64 + 16 * w + lr) * 1536 + 32 * ch + 8 * lc],
                     &Qn[(128 * w + 64 * ch + l) * 8]);
            gl2lds16(&qtg[(size_t)(16 * w + lr) * 1024 + qt * 64 + 32 * ch + 8 * lc],
                     &Qt[(128 * w + 64 * ch + l) * 8]);
        }
        if (t < 64) Ls[t] = L[(size_t)bh * 1024 + qt * 64 + t];
        __syncthreads();
        // S''[q][k]: rows q (4 i-tiles), cols k (2 jj per wave); P''^T into Ps
        #pragma unroll
        for (int i = 0; i < 4; ++i) {
            bf16x8 a0 = *(const bf16x8*)&Qn[(128 * i + l) * 8];
            bf16x8 a1 = *(const bf16x8*)&Qn[(128 * i + 64 + l) * 8];
            f32x4 lv = *(const f32x4*)&Ls[16 * i + 4 * g];
            #pragma unroll
            for (int jj = 0; jj < 2; ++jj) {
                f32x4 z = {0.f, 0.f, 0.f, 0.f};
                z = MFMA(a0, KF[jj][0], z, 0, 0, 0);
                z = MFMA(a1, KF[jj][1], z, 0, 0, 0);
                u16x4 pv;
                #pragma unroll
                for (int r = 0; r < 4; ++r)
                    pv[r] = f2bf(__expf(fmaf(z[r], BETA_, -lv[r])));
                *(u16x4*)&Ps[(128 * (2 * w + jj) + 32 * i + 16 * (g >> 1) + cid) * 8 + 4 * (g & 1)] = pv;
            }
        }
        // Ak += P''^T . Q  (A = Ps rows k, B = Qt rows y)
        #pragma unroll
        for (int jj = 0; jj < 2; ++jj) {
            bf16x8 p0 = *(const bf16x8*)&Ps[(128 * (2 * w + jj) + l) * 8];
            bf16x8 p1 = *(const bf16x8*)&Ps[(128 * (2 * w + jj) + 64 + l) * 8];
            #pragma unroll
            for (int j = 0; j < 4; ++j) {
                acc[jj][j] = MFMA(p0, *(const bf16x8*)&Qt[(128 * j + l) * 8], acc[jj][j], 0, 0, 0);
                acc[jj][j] = MFMA(p1, *(const bf16x8*)&Qt[(128 * j + 64 + l) * 8], acc[jj][j], 0, 0, 0);
            }
        }
    }
    #pragma unroll
    for (int jj = 0; jj < 2; ++jj)
        #pragma unroll
        for (int r = 0; r < 4; ++r) {
            int row = k0 + 32 * w + 16 * jj + 4 * g + r;
            #pragma unroll
            for (int j = 0; j < 4; ++j)
                mid[(size_t)(b * 1024 + row) * 4608 + 768 + h * 64 + 16 * j + cid] = f2bf(acc[jj][j][r]);
        }
}

// ---------------------------------------------------------------------------
extern "C" void kernel_launch(void* const* d_in, const int* in_sizes, int n_in,
                              void* d_out, int out_size, void* d_ws, size_t ws_size,
                              hipStream_t stream)
{
    const float* x     = (const float*)d_in[0];
    const float* gamma = (const float*)d_in[1];
    const float* betap = (const float*)d_in[2];
    const float* Wq    = (const float*)d_in[3];
    const float* Wk    = (const float*)d_in[4];
    const float* xi    = (const float*)d_in[5];
    float* xc = (float*)d_out;

    char* p = (char*)d_ws;
    u16* wqk_bf   = (u16*)p; p += (size_t)1536 * 768 * 2;
    u16* xi_bf    = (u16*)p; p += (size_t)3072 * 768 * 2;
    u16* wcatT_bf = (u16*)p; p += (size_t)768 * 4608 * 2;
    u16* g_bf     = (u16*)p; p += (size_t)NTOK * 768 * 2;
    u16* qk_bf    = (u16*)p; p += (size_t)NTOK * 1536 * 2;
    u16* qkT_bf   = (u16*)p; p += (size_t)96 * 2 * 64 * 1024 * 2;
    u16* mid_bf   = (u16*)p; p += (size_t)NTOK * 4608 * 2;
    float* L      = (float*)p; p += (size_t)96 * 1024 * 4;
    (void)ws_size; (void)in_sizes; (void)n_in; (void)out_size;

    hipMemcpyAsync(xc, x, (size_t)NTOK * 768 * 4, hipMemcpyDeviceToDevice, stream);

    convert_bf<<<576, 256, 0, stream>>>(Wq, wqk_bf, 147456);
    convert_bf<<<576, 256, 0, stream>>>(Wk, wqk_bf + 768 * 768, 147456);
    convert_bf<<<2304, 256, 0, stream>>>(xi, xi_bf, 589824);
    transpose_bf<<<dim3(72, 12), 256, 0, stream>>>(Wq, Wk, xi, wcatT_bf);

    for (int step = 0; step < STEPS_; ++step) {
        ln_kernel<<<NTOK, 256, 0, stream>>>(xc, gamma, betap, g_bf);
        // qk = g.[Wq;Wk]^T  (bf16 natural + transposed copies)
        gemm128<3><<<dim3(64, 12), 256, 0, stream>>>(
            g_bf, 768, wqk_bf, 768, qk_bf, 1536, 768, 0.0f, qkT_bf);
        // mid[:,1536:] = relu(g.xi^T)
        gemm128<1><<<dim3(64, 24), 256, 0, stream>>>(
            g_bf, 768, xi_bf, 768, mid_bf + 1536, 4608, 768, 0.0f, (u16*)0);
        // Aq (+L), Ak
        dq_kernel<<<dim3(8, 96), 256, 0, stream>>>(qk_bf, qkT_bf, L, mid_bf);
        dk_kernel<<<dim3(8, 96), 256, 0, stream>>>(qk_bf, qkT_bf, L, mid_bf);
        // xc += alpha * mid . Wcat  (K=4608 fused)
        gemm128<2><<<dim3(64, 6), 256, 0, stream>>>(
            mid_bf, 4608, wcatT_bf, 4608, xc, 768, 4608, ALPHA_, (u16*)0);
    }
}